// Round 1
// baseline (457.607 us; speedup 1.0000x reference)
//
#include <hip/hip_runtime.h>
#include <hip/hip_bf16.h>

typedef __attribute__((ext_vector_type(8))) short short8;
typedef __attribute__((ext_vector_type(4))) float f32x4;

#define LL 16
#define NP3 23
#define NP2 4
#define NE 10
#define NC 128
#define KPACK 368       // 16*23 fused (i,k)
#define KTOT 384        // padded to 12 * 32
#define NTOT 256        // (w,x)
#define MT 64           // rows per block
#define ZPAD 392        // KTOT + 8 bf16 -> 784 B row stride (breaks bank alias)
#define CPAD 260

// ---------------- kernel 1: pack U3/U2 -> bf16 B^T [256][384] ----------------
__global__ void build_B(const float* __restrict__ U3, const float* __restrict__ U2,
                        __hip_bfloat16* __restrict__ Bm) {
    int n  = blockIdx.x;    // 0..255 = w*16+x
    int kk = threadIdx.x;   // 0..383
    float v = 0.f;
    if (kk < KPACK) {
        int i = kk / NP3, k = kk - i * NP3;
        v = U3[(n * LL + i) * NP3 + k];          // U3[w][x][i][k]
    } else if (kk < KPACK + NP2) {
        v = U2[n * NP2 + (kk - KPACK)];          // U2[w][x][k2]
    }
    Bm[n * KTOT + kk] = __float2bfloat16(v);
}

// ---------------- kernel 2: fused contraction ----------------
__global__ __launch_bounds__(256, 2)
void contract_k(const float* __restrict__ x, const float* __restrict__ y,
                const float* __restrict__ W3, const float* __restrict__ W2,
                const float* __restrict__ W1, const float* __restrict__ U1,
                const __hip_bfloat16* __restrict__ Bm, float* __restrict__ out) {
    __shared__ __align__(16) char zcbuf[CPAD * MT * 4];   // union: Zt (bf16) then Ct (f32)
    __shared__ float xs[MT][17];                          // +1 pad: conflict-free row reads
    __shared__ float wys[MT][28];                         // [0..22]=Wy3 [23..26]=Wy2 [27]=Wy1

    __hip_bfloat16 (*Zt)[ZPAD] = reinterpret_cast<__hip_bfloat16 (*)[ZPAD]>(zcbuf);
    float (*Ct)[CPAD]          = reinterpret_cast<float (*)[CPAD]>(zcbuf);

    const int tid = threadIdx.x;
    const int m0  = blockIdx.x * MT;

    // phase 1: stage x rows (coalesced: 1024 contiguous floats)
    for (int idx = tid; idx < MT * LL; idx += 256) {
        int r = idx >> 4, i = idx & 15;
        xs[r][i] = x[(size_t)m0 * LL + idx];
    }

    // phase 2: Wy = y . W  (4 threads per row, 7 outputs each)
    {
        int r = tid >> 2, p = tid & 3;
        int m = m0 + r;
        int b = m >> 7, c = m & (NC - 1);
        const float* yr = y + b * NE;
        for (int j = 0; j < 7; ++j) {
            int idx = p * 7 + j;
            float s = 0.f;
            if (idx < NP3) {
                for (int e = 0; e < NE; ++e) s += yr[e] * W3[(e * NP3 + idx) * NC + c];
            } else if (idx < NP3 + NP2) {
                int k2 = idx - NP3;
                for (int e = 0; e < NE; ++e) s += yr[e] * W2[(e * NP2 + k2) * NC + c];
            } else {
                for (int e = 0; e < NE; ++e) s += yr[e] * W1[e * NC + c];
            }
            wys[r][idx] = s;
        }
    }
    __syncthreads();

    // phase 3: Z-tile (bf16): Z[r][i*23+k] = x_i * Wy3_k ; [368..371] = Wy2 ; rest 0
    {
        int r = tid >> 2, q = tid & 3;
        int kk0 = q * (KTOT / 4);
        for (int kk = kk0; kk < kk0 + KTOT / 4; ++kk) {
            float v = 0.f;
            if (kk < KPACK) {
                int i = kk / NP3, k = kk - i * NP3;
                v = xs[r][i] * wys[r][k];
            } else if (kk < KPACK + NP2) {
                v = wys[r][NP3 + (kk - KPACK)];
            }
            Zt[r][kk] = __float2bfloat16(v);
        }
    }
    __syncthreads();

    // phase 4: GEMM  c2[64 x 256] = Z[64 x 384] * B^T[256 x 384]^T
    const int lane = tid & 63;
    const int wv   = tid >> 6;       // wave id: 16 M-rows each
    const int ar   = lane & 15;
    const int kg   = lane >> 4;
    f32x4 acc[16];
#pragma unroll
    for (int i = 0; i < 16; ++i) acc[i] = f32x4{0.f, 0.f, 0.f, 0.f};

    const unsigned short* Bmu = reinterpret_cast<const unsigned short*>(Bm);
#pragma unroll
    for (int s = 0; s < KTOT / 32; ++s) {
        const int kk0 = s * 32 + kg * 8;
        short8 afrag = *reinterpret_cast<const short8*>(&Zt[wv * 16 + ar][kk0]);
#pragma unroll
        for (int nf = 0; nf < 16; ++nf) {
            int n = nf * 16 + ar;
            short8 bfrag = *reinterpret_cast<const short8*>(Bmu + n * KTOT + kk0);
            acc[nf] = __builtin_amdgcn_mfma_f32_16x16x32_bf16(afrag, bfrag, acc[nf], 0, 0, 0);
        }
    }
    __syncthreads();   // all Zt reads done before Ct aliases the buffer

    // store C frags: D row=(lane>>4)*4+q (M), col=lane&15 (N)
#pragma unroll
    for (int nf = 0; nf < 16; ++nf) {
#pragma unroll
        for (int q = 0; q < 4; ++q) {
            Ct[wv * 16 + kg * 4 + q][nf * 16 + ar] = acc[nf][q];
        }
    }
    __syncthreads();

    // epilogue: out[m] = sum_w x_w * ( sum_x c2[w,x]*x_x + U1[w]*Wy1 )
    {
        int r = tid >> 2, p = tid & 3;
        float wy1 = wys[r][27];
        float s = 0.f;
#pragma unroll
        for (int ww = 0; ww < 4; ++ww) {
            int w = p * 4 + ww;
            float t = 0.f;
#pragma unroll
            for (int xx = 0; xx < LL; ++xx) t += Ct[r][w * 16 + xx] * xs[r][xx];
            s += xs[r][w] * (t + U1[w] * wy1);
        }
        s += __shfl_xor(s, 1);
        s += __shfl_xor(s, 2);
        if (p == 0) out[m0 + r] = s;
    }
}

extern "C" void kernel_launch(void* const* d_in, const int* in_sizes, int n_in,
                              void* d_out, int out_size, void* d_ws, size_t ws_size,
                              hipStream_t stream) {
    const float* x  = (const float*)d_in[0];
    const float* y  = (const float*)d_in[1];
    const float* U3 = (const float*)d_in[2];
    const float* U2 = (const float*)d_in[3];
    const float* U1 = (const float*)d_in[4];
    const float* W3 = (const float*)d_in[5];
    const float* W2 = (const float*)d_in[6];
    const float* W1 = (const float*)d_in[7];
    __hip_bfloat16* Bm = (__hip_bfloat16*)d_ws;   // 256*384*2 = 196608 B

    build_B<<<256, 384, 0, stream>>>(U3, U2, Bm);
    contract_k<<<4096, 256, 0, stream>>>(x, y, W3, W2, W1, U1, Bm, (float*)d_out);
}

// Round 2
// 131.564 us; speedup vs baseline: 3.4782x; 3.4782x over previous
//
#include <hip/hip_runtime.h>
#include <hip/hip_bf16.h>

typedef __attribute__((ext_vector_type(8))) short short8;
typedef __attribute__((ext_vector_type(4))) float f32x4;

#define LL 16
#define NP3 23
#define NE 10
#define NC 128
#define KI 24            // per-i stride: 23 U3 slots + 1 shared U2/zero slot
#define KTOT 384         // 16 * 24 = 12 k-steps of 32
#define NSTEPS 12
#define MT 64            // M rows per block
#define THREADS 512
#define WAVES 8
#define ZPAD 392         // 384 + 8 bf16 -> 784 B row stride (odd multiple of 16B)

// ---- kernel 1: pack U3/U2 -> fragment-major bf16 B  [ (s,n16) ][ lane ][ 8 ] ----
// element j of lane (ar=lane&15, kg=lane>>4) = B[n16*16+ar][s*32+kg*8+j]
// B[n][i*24+k] = k<23 ? U3[w=n>>4][x=n&15][i][k] : (i<4 ? U2[n][i] : 0)
__global__ void build_B(const float* __restrict__ U3, const float* __restrict__ U2,
                        __hip_bfloat16* __restrict__ Bf) {
    int s    = blockIdx.x >> 4;
    int n16  = blockIdx.x & 15;
    int lane = threadIdx.x;
    int ar   = lane & 15, kg = lane >> 4;
    int n    = n16 * 16 + ar;
    __hip_bfloat16 vals[8];
#pragma unroll
    for (int j = 0; j < 8; ++j) {
        int kk = s * 32 + kg * 8 + j;
        int i  = kk / KI, k = kk - i * KI;
        float v;
        if (k < NP3)      v = U3[((size_t)n * LL + i) * NP3 + k];
        else if (i < 4)   v = U2[n * 4 + i];
        else              v = 0.f;
        vals[j] = __float2bfloat16(v);
    }
    *reinterpret_cast<short8*>(Bf + ((size_t)blockIdx.x * 64 + lane) * 8) =
        *reinterpret_cast<short8*>(vals);
}

// ---- kernel 2: fused contraction ----
__global__ __launch_bounds__(THREADS, 4)
void contract_k(const float* __restrict__ x, const float* __restrict__ y,
                const float* __restrict__ W3, const float* __restrict__ W2,
                const float* __restrict__ W1, const float* __restrict__ U1,
                const __hip_bfloat16* __restrict__ Bf, float* __restrict__ out) {
    __shared__ __align__(16) __hip_bfloat16 Zt[MT][ZPAD];  // 50.2 KB
    __shared__ float xs[MT][17];
    __shared__ float wys[MT][28];   // [0..22]=Wy3 [23..26]=Wy2 [27]=Wy1
    __shared__ float part[MT][WAVES];

    const int tid = threadIdx.x;
    const int m0  = blockIdx.x * MT;

    // phase 1: stage x rows (1024 contiguous floats)
    for (int idx = tid; idx < MT * LL; idx += THREADS) {
        xs[idx >> 4][idx & 15] = x[(size_t)m0 * LL + idx];
    }

    // phase 2: Wy = y . W   (8 threads per row, 4 outputs each, 28 used)
    {
        int r = tid >> 3, p = tid & 7;
        int m = m0 + r;
        int c = m & (NC - 1);
        const float* yr = y + (size_t)(m >> 7) * NE;
        float yv[NE];
#pragma unroll
        for (int e = 0; e < NE; ++e) yv[e] = yr[e];
#pragma unroll
        for (int j = 0; j < 4; ++j) {
            int idx = p * 4 + j;
            if (idx < 28) {
                float s = 0.f;
                if (idx < NP3) {
#pragma unroll
                    for (int e = 0; e < NE; ++e) s += yv[e] * W3[(e * NP3 + idx) * NC + c];
                } else if (idx < 27) {
                    int k2 = idx - NP3;
#pragma unroll
                    for (int e = 0; e < NE; ++e) s += yv[e] * W2[(e * 4 + k2) * NC + c];
                } else {
#pragma unroll
                    for (int e = 0; e < NE; ++e) s += yv[e] * W1[e * NC + c];
                }
                wys[r][idx] = s;
            }
        }
    }
    __syncthreads();

    // phase 3: Z-tile bf16: Z[r][i*24+k] = x_i*Wy3_k (k<23); slot 23: i<4 -> Wy2_i
    {
        int r = tid >> 3, p = tid & 7;
        float wv[NP3];
#pragma unroll
        for (int k = 0; k < NP3; ++k) wv[k] = wys[r][k];
#pragma unroll
        for (int ii = 0; ii < 2; ++ii) {
            int i = p * 2 + ii;
            float xi   = xs[r][i];
            float slot = (i < 4) ? wys[r][NP3 + i] : 0.f;
            __hip_bfloat162* dst = reinterpret_cast<__hip_bfloat162*>(&Zt[r][i * KI]);
#pragma unroll
            for (int kp = 0; kp < 12; ++kp) {
                float a = xi * wv[2 * kp];
                float b = (kp < 11) ? xi * wv[2 * kp + 1] : slot;
                __hip_bfloat162 pk;
                pk.x = __float2bfloat16(a);
                pk.y = __float2bfloat16(b);
                dst[kp] = pk;
            }
        }
    }
    __syncthreads();

    // phase 4: GEMM — wave nw owns N columns [nw*32, nw*32+32), all 64 M rows
    const int lane = tid & 63;
    const int nw   = tid >> 6;
    const int ar   = lane & 15;
    const int kg   = lane >> 4;
    f32x4 acc[4][2];
#pragma unroll
    for (int mt = 0; mt < 4; ++mt)
#pragma unroll
        for (int nf = 0; nf < 2; ++nf) acc[mt][nf] = f32x4{0.f, 0.f, 0.f, 0.f};

    const short8* Bv = reinterpret_cast<const short8*>(Bf);
#pragma unroll
    for (int s = 0; s < NSTEPS; ++s) {
        short8 b0 = Bv[((size_t)(s * 16 + nw * 2 + 0)) * 64 + lane];  // coalesced 1KB/wave
        short8 b1 = Bv[((size_t)(s * 16 + nw * 2 + 1)) * 64 + lane];
#pragma unroll
        for (int mt = 0; mt < 4; ++mt) {
            short8 a = *reinterpret_cast<const short8*>(&Zt[mt * 16 + ar][s * 32 + kg * 8]);
            acc[mt][0] = __builtin_amdgcn_mfma_f32_16x16x32_bf16(a, b0, acc[mt][0], 0, 0, 0);
            acc[mt][1] = __builtin_amdgcn_mfma_f32_16x16x32_bf16(a, b1, acc[mt][1], 0, 0, 0);
        }
    }

    // epilogue: per-lane contract with x_x (=ar lane) and x_w, 16-lane reduce
    // acc[mt][nf][q] = c2[row = mt*16+kg*4+q][w = nw*2+nf][x = ar]
#pragma unroll
    for (int mt = 0; mt < 4; ++mt) {
#pragma unroll
        for (int q = 0; q < 4; ++q) {
            int row  = mt * 16 + kg * 4 + q;
            float xx = xs[row][ar];
            float sl = xx * (acc[mt][0][q] * xs[row][nw * 2] +
                             acc[mt][1][q] * xs[row][nw * 2 + 1]);
            sl += __shfl_xor(sl, 1);
            sl += __shfl_xor(sl, 2);
            sl += __shfl_xor(sl, 4);
            sl += __shfl_xor(sl, 8);
            if (ar == 0) part[row][nw] = sl;
        }
    }
    __syncthreads();

    if (tid < MT) {
        int r = tid;
        float s = 0.f;
#pragma unroll
        for (int w8 = 0; w8 < WAVES; ++w8) s += part[r][w8];
        float du = 0.f;
#pragma unroll
        for (int w = 0; w < LL; ++w) du += U1[w] * xs[r][w];
        out[m0 + r] = s + wys[r][27] * du;
    }
}

extern "C" void kernel_launch(void* const* d_in, const int* in_sizes, int n_in,
                              void* d_out, int out_size, void* d_ws, size_t ws_size,
                              hipStream_t stream) {
    const float* x  = (const float*)d_in[0];
    const float* y  = (const float*)d_in[1];
    const float* U3 = (const float*)d_in[2];
    const float* U2 = (const float*)d_in[3];
    const float* U1 = (const float*)d_in[4];
    const float* W3 = (const float*)d_in[5];
    const float* W2 = (const float*)d_in[6];
    const float* W1 = (const float*)d_in[7];
    __hip_bfloat16* Bf = (__hip_bfloat16*)d_ws;   // 192 * 64 * 8 * 2 = 196608 B

    build_B<<<NSTEPS * 16, 64, 0, stream>>>(U3, U2, Bf);
    contract_k<<<4096, THREADS, 0, stream>>>(x, y, W3, W2, W1, U1, Bf, (float*)d_out);
}

// Round 3
// 126.872 us; speedup vs baseline: 3.6068x; 1.0370x over previous
//
#include <hip/hip_runtime.h>
#include <hip/hip_bf16.h>

typedef __attribute__((ext_vector_type(8))) short short8;
typedef __attribute__((ext_vector_type(4))) float f32x4;

#define LL 16
#define NP3 23
#define NE 10
#define NC 128
#define KI 24            // per-i K stride: 23 U3 slots + 1 U2/zero slot; 16*24 = 384 = 12 k-steps
#define NSTEPS 12
#define MT 64            // M rows per block (one b per block)
#define THREADS 1024
#define NWAVES 16
#define ZCOLS 392        // 784 B row stride = 196 dw (16B-aligned, 2-way-free reads)

// ---- kernel 1: pack U3/U2 -> fragment-major bf16 B  [(s,n16)][lane][8] ----
// element j of lane (ar=lane&15, kg=lane>>4) = B[n16*16+ar][s*32+kg*8+j]
// B[n][i*24+k] = k<23 ? U3[w=n>>4][x=n&15][i][k] : (i<4 ? U2[n][i] : 0)
__global__ void build_B(const float* __restrict__ U3, const float* __restrict__ U2,
                        __hip_bfloat16* __restrict__ Bf) {
    int s    = blockIdx.x >> 4;
    int n16  = blockIdx.x & 15;
    int lane = threadIdx.x;
    int ar   = lane & 15, kg = lane >> 4;
    int n    = n16 * 16 + ar;
    __hip_bfloat16 vals[8];
#pragma unroll
    for (int j = 0; j < 8; ++j) {
        int kk = s * 32 + kg * 8 + j;
        int i  = kk / KI, k = kk - i * KI;
        float v;
        if (k < NP3)      v = U3[((size_t)n * LL + i) * NP3 + k];
        else if (i < 4)   v = U2[n * 4 + i];
        else              v = 0.f;
        vals[j] = __float2bfloat16(v);
    }
    *reinterpret_cast<short8*>(Bf + ((size_t)blockIdx.x * 64 + lane) * 8) =
        *reinterpret_cast<short8*>(vals);
}

// ---- kernel 2: fused contraction ----
__global__ __launch_bounds__(THREADS, 8)
void contract_k(const float* __restrict__ x, const float* __restrict__ y,
                const float* __restrict__ W3, const float* __restrict__ W2,
                const float* __restrict__ W1, const float* __restrict__ U1,
                const __hip_bfloat16* __restrict__ Bf, float* __restrict__ out) {
    __shared__ __align__(16) __hip_bfloat16 Zt[MT][ZCOLS];   // 50176 B
    __shared__ float xs[MT][16];                             // 4096 B
    __shared__ float wys[MT][28];                            // 7168 B  [0..22]=Wy3 [23..26]=Wy2 [27]=Wy1
    // part[64][16] aliased onto Zt (guarded by barrier after GEMM)
    float (*part)[NWAVES] = reinterpret_cast<float (*)[NWAVES]>(&Zt[0][0]);

    const int tid = threadIdx.x;
    const int m0  = blockIdx.x * MT;
    const int b   = m0 >> 7;            // uniform per block
    const int c0  = m0 & (NC - 1);

    // phase 1: stage x rows (1024 contiguous floats, one per thread)
    xs[tid >> 4][tid & 15] = x[(size_t)m0 * LL + tid];

    // phase 2: wys[r][idx] = sum_e y[b,e] * W(e,idx,c0+r)  — coalesced over r
    float yv[NE];
#pragma unroll
    for (int e = 0; e < NE; ++e) yv[e] = y[(size_t)b * NE + e];   // uniform -> scalar loads

    for (int u = tid; u < 28 * MT; u += THREADS) {
        int idx = u >> 6, r = u & 63;
        int c = c0 + r;
        float s = 0.f;
        if (idx < NP3) {
#pragma unroll
            for (int e = 0; e < NE; ++e) s += yv[e] * W3[(e * NP3 + idx) * NC + c];
        } else if (idx < 27) {
            int k2 = idx - NP3;
#pragma unroll
            for (int e = 0; e < NE; ++e) s += yv[e] * W2[(e * 4 + k2) * NC + c];
        } else {
#pragma unroll
            for (int e = 0; e < NE; ++e) s += yv[e] * W1[e * NC + c];
        }
        wys[r][idx] = s;
    }
    __syncthreads();

    // phase 3: Z[r][i*24+k] = x_i*Wy3_k (k<23); slot k=23: i<4 ? Wy2_i : 0
    // thread = (r = tid>>4, i = tid&15) owns one 24-element segment -> 3x ds_write_b128
    {
        int r = tid >> 4, i = tid & 15;
        float xi = xs[r][i];
        __hip_bfloat162 pk[12];
#pragma unroll
        for (int kp = 0; kp < 12; ++kp) {
            float a  = xi * wys[r][2 * kp];
            float bb = (kp < 11) ? xi * wys[r][2 * kp + 1]
                                 : ((i < 4) ? wys[r][NP3 + i] : 0.f);
            pk[kp].x = __float2bfloat16(a);
            pk[kp].y = __float2bfloat16(bb);
        }
        const short8* pv = reinterpret_cast<const short8*>(pk);
        short8* dst = reinterpret_cast<short8*>(&Zt[r][i * KI]);
        dst[0] = pv[0]; dst[1] = pv[1]; dst[2] = pv[2];
    }
    __syncthreads();

    // phase 4: GEMM — wave nw owns N cols [nw*16, nw*16+16)  (w = nw, x = ar)
    const int lane = tid & 63;
    const int nw   = tid >> 6;
    const int ar   = lane & 15;
    const int kg   = lane >> 4;
    f32x4 acc[4];
#pragma unroll
    for (int mt = 0; mt < 4; ++mt) acc[mt] = f32x4{0.f, 0.f, 0.f, 0.f};

    const short8* Bw = reinterpret_cast<const short8*>(Bf) + (size_t)nw * 64 + lane;
    short8 bcur = Bw[0];                      // depth-1 prefetch pipeline
#pragma unroll
    for (int s = 0; s < NSTEPS; ++s) {
        short8 bnxt = bcur;
        if (s + 1 < NSTEPS) bnxt = Bw[(size_t)(s + 1) * 1024];
#pragma unroll
        for (int mt = 0; mt < 4; ++mt) {
            short8 a = *reinterpret_cast<const short8*>(&Zt[mt * 16 + ar][s * 32 + kg * 8]);
            acc[mt] = __builtin_amdgcn_mfma_f32_16x16x32_bf16(a, bcur, acc[mt], 0, 0, 0);
        }
        bcur = bnxt;
    }
    __syncthreads();    // all Zt reads complete before part aliases it

    // epilogue: acc[mt][q] = c2[row = mt*16+kg*4+q][w=nw][x=ar]
    // sum over x via 16-lane shfl reduce, then * x_w
#pragma unroll
    for (int mt = 0; mt < 4; ++mt) {
#pragma unroll
        for (int q = 0; q < 4; ++q) {
            int row = mt * 16 + kg * 4 + q;
            float sl = acc[mt][q] * xs[row][ar];
            sl += __shfl_xor(sl, 1);
            sl += __shfl_xor(sl, 2);
            sl += __shfl_xor(sl, 4);
            sl += __shfl_xor(sl, 8);
            if (ar == 0) part[row][nw] = xs[row][nw] * sl;
        }
    }
    __syncthreads();

    // final combine + U1 term
    if (tid < MT) {
        int r = tid;
        float s = 0.f;
#pragma unroll
        for (int w = 0; w < NWAVES; ++w) s += part[r][w];
        float du = 0.f;
#pragma unroll
        for (int w = 0; w < LL; ++w) du += U1[w] * xs[r][w];
        out[m0 + r] = s + wys[r][27] * du;
    }
}

extern "C" void kernel_launch(void* const* d_in, const int* in_sizes, int n_in,
                              void* d_out, int out_size, void* d_ws, size_t ws_size,
                              hipStream_t stream) {
    const float* x  = (const float*)d_in[0];
    const float* y  = (const float*)d_in[1];
    const float* U3 = (const float*)d_in[2];
    const float* U2 = (const float*)d_in[3];
    const float* U1 = (const float*)d_in[4];
    const float* W3 = (const float*)d_in[5];
    const float* W2 = (const float*)d_in[6];
    const float* W1 = (const float*)d_in[7];
    __hip_bfloat16* Bf = (__hip_bfloat16*)d_ws;   // 192 * 64 * 8 * 2 = 196608 B

    build_B<<<NSTEPS * 16, 64, 0, stream>>>(U3, U2, Bf);
    contract_k<<<4096, THREADS, 0, stream>>>(x, y, W3, W2, W1, U1, Bf, (float*)d_out);
}

// Round 4
// 115.990 us; speedup vs baseline: 3.9452x; 1.0938x over previous
//
#include <hip/hip_runtime.h>
#include <hip/hip_bf16.h>

typedef __attribute__((ext_vector_type(8))) short short8;
typedef __attribute__((ext_vector_type(16))) float f32x16;

#define LL 16
#define NP3 23
#define NE 10
#define NC 128
#define KI 24            // fused K stride per i: 23 U3 slots + 1 U2/zero slot
#define NSK 24           // K-steps (384/16) per N-tile
#define NT 8             // N-tiles of 32 cols (256 total)
#define MB 128           // rows per block (= one b)
#define THREADS 256

static __device__ __forceinline__ short f2bs(float f) {
    __hip_bfloat16 h = __float2bfloat16(f);
    short s;
    __builtin_memcpy(&s, &h, 2);
    return s;
}

// ---- kernel 1: pack U3/U2 -> fragment-major bf16 B for 32x32x16 ----
// frag g = t*24+s ; lane: col = t*32+(lane&31), k = s*16+(lane>>5)*8+j
// B[n][K], K = i*24+kk : kk<23 ? U3[n][i][kk] : (i<4 ? U2[n][i] : 0)
__global__ void build_B(const float* __restrict__ U3, const float* __restrict__ U2,
                        __hip_bfloat16* __restrict__ Bf) {
    int g = blockIdx.x;              // 0..191
    int t = g / NSK, s = g % NSK;
    int lane = threadIdx.x;
    int col  = t * 32 + (lane & 31);
    int hi   = lane >> 5;
    short8 v;
#pragma unroll
    for (int j = 0; j < 8; ++j) {
        int K = s * 16 + hi * 8 + j;
        int i = K / KI, kk = K - i * KI;
        float f;
        if (kk < NP3)    f = U3[((size_t)col * LL + i) * NP3 + kk];
        else if (i < 4)  f = U2[col * 4 + i];
        else             f = 0.f;
        v[j] = f2bs(f);
    }
    *reinterpret_cast<short8*>(Bf + ((size_t)g * 64 + lane) * 8) = v;
}

// A-build: s,j unrolled -> K compile-time -> register-indexed xr/wr fold statically
#define BUILD_A(HIOFF)                                                        \
    _Pragma("unroll")                                                         \
    for (int s = 0; s < NSK; ++s) {                                           \
        short8 av;                                                            \
        _Pragma("unroll")                                                     \
        for (int j = 0; j < 8; ++j) {                                         \
            const int K  = s * 16 + (HIOFF) + j;                              \
            const int i  = K / KI;                                            \
            const int kk = K - i * KI;                                        \
            float f = (kk < NP3) ? xr[i] * wr[kk]                             \
                                 : ((i < 4) ? w2r[i] : 0.f);                  \
            av[j] = f2bs(f);                                                  \
        }                                                                     \
        A[s] = av;                                                            \
    }

// ---- kernel 2: fused contraction, A in registers, B streamed from L2 ----
__global__ __launch_bounds__(THREADS, 2)
void contract_k(const float* __restrict__ x, const float* __restrict__ y,
                const float* __restrict__ W3, const float* __restrict__ W2,
                const float* __restrict__ W1, const float* __restrict__ U1,
                const __hip_bfloat16* __restrict__ Bf, float* __restrict__ out) {
    __shared__ float xs[MB][17];
    __shared__ float wys[MB][29];   // 0..22 Wy3, 23..26 Wy2, 27 Wy1, 28 du=U1.x

    const int tid = threadIdx.x;
    const int m0  = blockIdx.x * MB;
    const int b   = blockIdx.x;     // MB == NC -> one b per block

    // stage x rows (coalesced)
    for (int idx = tid; idx < MB * LL; idx += THREADS)
        xs[idx >> 4][idx & 15] = x[(size_t)m0 * LL + idx];
    __syncthreads();                 // xs needed by du below

    // Wy = y.W, coalesced over c (=r); plus du[r] = U1 . x[r]
    float yv[NE];
#pragma unroll
    for (int e = 0; e < NE; ++e) yv[e] = y[(size_t)b * NE + e];

    for (int u = tid; u < 29 * MB; u += THREADS) {
        int idx = u >> 7, r = u & (MB - 1);
        float s = 0.f;
        if (idx < NP3) {
#pragma unroll
            for (int e = 0; e < NE; ++e) s += yv[e] * W3[(e * NP3 + idx) * NC + r];
        } else if (idx < 27) {
#pragma unroll
            for (int e = 0; e < NE; ++e) s += yv[e] * W2[(e * 4 + (idx - NP3)) * NC + r];
        } else if (idx == 27) {
#pragma unroll
            for (int e = 0; e < NE; ++e) s += yv[e] * W1[e * NC + r];
        } else {
#pragma unroll
            for (int w = 0; w < LL; ++w) s += U1[w] * xs[r][w];
        }
        wys[r][idx] = s;
    }
    __syncthreads();

    // per-lane geometry
    const int lane = tid & 63;
    const int wb   = tid >> 6;          // wave id: rows [wb*32, wb*32+32)
    const int l31  = lane & 31;
    const int hi   = lane >> 5;
    const int bsel = l31 >> 4;          // which w within a 32-col tile
    const int arow = wb * 32 + l31;     // this lane's A row

    // build A fragments (96 VGPR): A[s] holds Z[arow][s*16 + hi*8 .. +8]
    short8 A[NSK];
    {
        float xr[LL], wr[NP3], w2r[4];
#pragma unroll
        for (int i = 0; i < LL; ++i) xr[i] = xs[arow][i];
#pragma unroll
        for (int k = 0; k < NP3; ++k) wr[k] = wys[arow][k];
#pragma unroll
        for (int i = 0; i < 4; ++i) w2r[i] = wys[arow][NP3 + i];
        if (hi == 0) { BUILD_A(0) } else { BUILD_A(8) }
    }

    // xx[q] = x[row(q)][col&15]  (col&15 == lane&15 for every tile)
    float xx[16];
#pragma unroll
    for (int q = 0; q < 16; ++q) {
        int rowq = (wb << 5) + (q & 3) + ((q >> 2) << 3) + (hi << 2);
        xx[q] = xs[rowq][lane & 15];
    }

    // main loop: stream B with depth-6 register pipeline, fold per tile
    const short8* Bv = reinterpret_cast<const short8*>(Bf);
    short8 bf[6];
#pragma unroll
    for (int j = 0; j < 6; ++j) bf[j] = Bv[(size_t)j * 64 + lane];

    float acc_out[16];
#pragma unroll
    for (int q = 0; q < 16; ++q) acc_out[q] = 0.f;

#pragma unroll
    for (int t = 0; t < NT; ++t) {
        f32x16 acc;
#pragma unroll
        for (int q = 0; q < 16; ++q) acc[q] = 0.f;
#pragma unroll
        for (int s = 0; s < NSK; ++s) {
            const int g = t * NSK + s;
            acc = __builtin_amdgcn_mfma_f32_32x32x16_bf16(A[s], bf[g % 6], acc, 0, 0, 0);
            if (g + 6 < NT * NSK)
                bf[g % 6] = Bv[(size_t)(g + 6) * 64 + lane];
        }
        // fold tile t: col = t*32 + l31 ; w = 2t + bsel ; x = lane&15
#pragma unroll
        for (int q = 0; q < 16; ++q) {
            int rowq = (wb << 5) + (q & 3) + ((q >> 2) << 3) + (hi << 2);
            float xw = xs[rowq][2 * t + bsel];
            acc_out[q] += acc[q] * xx[q] * xw;
        }
    }

    // butterfly over the 32-lane half (rows depend on (q,hi) only), then write
#pragma unroll
    for (int q = 0; q < 16; ++q) {
        float v = acc_out[q];
        v += __shfl_xor(v, 1);
        v += __shfl_xor(v, 2);
        v += __shfl_xor(v, 4);
        v += __shfl_xor(v, 8);
        v += __shfl_xor(v, 16);
        if (l31 == 0) {
            int rowq = (wb << 5) + (q & 3) + ((q >> 2) << 3) + (hi << 2);
            out[m0 + rowq] = v + wys[rowq][27] * wys[rowq][28];
        }
    }
}

extern "C" void kernel_launch(void* const* d_in, const int* in_sizes, int n_in,
                              void* d_out, int out_size, void* d_ws, size_t ws_size,
                              hipStream_t stream) {
    const float* x  = (const float*)d_in[0];
    const float* y  = (const float*)d_in[1];
    const float* U3 = (const float*)d_in[2];
    const float* U2 = (const float*)d_in[3];
    const float* U1 = (const float*)d_in[4];
    const float* W3 = (const float*)d_in[5];
    const float* W2 = (const float*)d_in[6];
    const float* W1 = (const float*)d_in[7];
    __hip_bfloat16* Bf = (__hip_bfloat16*)d_ws;   // 192 frags * 64 lanes * 8 bf16 * 2B = 196608 B

    build_B<<<NT * NSK, 64, 0, stream>>>(U3, U2, Bf);
    contract_k<<<2048, THREADS, 0, stream>>>(x, y, W3, W2, W1, U1, Bf, (float*)d_out);
}